// Round 8
// baseline (463.856 us; speedup 1.0000x reference)
//
#include <hip/hip_runtime.h>
#include <hip/hip_bf16.h>

typedef __hip_bfloat16 bf16;
typedef __attribute__((ext_vector_type(8))) short short8;
typedef __attribute__((ext_vector_type(4))) float floatx4;
typedef __attribute__((address_space(3))) char c3;

template <int V> struct ic { static constexpr int value = V; };

__device__ __forceinline__ unsigned short f2bf(float x) {
  unsigned u = __builtin_bit_cast(unsigned, x);
  unsigned r = (u + 0x7fffu + ((u >> 16) & 1u)) >> 16;
  return (unsigned short)r;
}

#define GLL(g, l) __builtin_amdgcn_global_load_lds(                                  \
    (const __attribute__((address_space(1))) void*)(g),                              \
    (__attribute__((address_space(3))) void*)(l), 16, 0, 0)

template <int N> __device__ __forceinline__ void vmwait() {
  asm volatile("s_waitcnt vmcnt(%0)" ::"i"(N) : "memory");
}
template <int N> __device__ __forceinline__ void lgkwait() {
  asm volatile("s_waitcnt lgkmcnt(%0)" ::"i"(N) : "memory");
  __builtin_amdgcn_sched_barrier(0);
}
template <int OFF> __device__ __forceinline__ short8 dsr(unsigned a) {
  short8 r;
  asm volatile("ds_read_b128 %0, %1 offset:%2" : "=v"(r) : "v"(a), "i"(OFF));
  return r;
}
#define MFMA_(d, a, b) d = __builtin_amdgcn_mfma_f32_16x16x32_bf16(a, b, d, 0, 0, 0)

// ---------------- weight transpose+convert: fp32 [K][N] -> bf16 [N][K] ----------
__global__ __launch_bounds__(256) void wtrans_kernel(const float* __restrict__ in,
                                                     bf16* __restrict__ out,
                                                     int K, int N) {
  __shared__ float tile[32][33];
  int tx = threadIdx.x, ty = threadIdx.y;
  int n0 = blockIdx.x * 32, k0 = blockIdx.y * 32;
#pragma unroll
  for (int i = 0; i < 32; i += 8)
    tile[ty + i][tx] = in[(size_t)(k0 + ty + i) * N + (n0 + tx)];
  __syncthreads();
#pragma unroll
  for (int i = 0; i < 32; i += 8)
    out[(size_t)(n0 + ty + i) * K + (k0 + tx)] = __float2bfloat16(tile[tx][ty + i]);
}

// ---------------- LayerNorm fp32 -> bf16, D=1024, one block(256)/row ------------
__global__ __launch_bounds__(256) void ln_kernel(const float* __restrict__ x,
                                                 const float* __restrict__ g,
                                                 const float* __restrict__ b,
                                                 bf16* __restrict__ out) {
  const int D = 1024;
  size_t row = blockIdx.x;
  int t = threadIdx.x;
  float4 v = ((const float4*)(x + row * D))[t];
  float s  = v.x + v.y + v.z + v.w;
  float ss = v.x * v.x + v.y * v.y + v.z * v.z + v.w * v.w;
#pragma unroll
  for (int off = 32; off > 0; off >>= 1) {
    s  += __shfl_xor(s, off);
    ss += __shfl_xor(ss, off);
  }
  __shared__ float rs[4], rss[4];
  int wv = t >> 6;
  if ((t & 63) == 0) { rs[wv] = s; rss[wv] = ss; }
  __syncthreads();
  s  = rs[0] + rs[1] + rs[2] + rs[3];
  ss = rss[0] + rss[1] + rss[2] + rss[3];
  float mu  = s * (1.f / D);
  float inv = rsqrtf(ss * (1.f / D) - mu * mu + 1e-5f);
  float4 gv = ((const float4*)g)[t];
  float4 bv = ((const float4*)b)[t];
  ushort4 o;
  o.x = f2bf((v.x - mu) * inv * gv.x + bv.x);
  o.y = f2bf((v.y - mu) * inv * gv.y + bv.y);
  o.z = f2bf((v.z - mu) * inv * gv.z + bv.z);
  o.w = f2bf((v.w - mu) * inv * gv.w + bv.w);
  ((ushort4*)(out + row * D))[t] = o;
}

// ---------------- softmax: fp32 row (2048) -> bf16 written in place -------------
__global__ __launch_bounds__(256) void softmax_kernel(float* sc) {
  const int S = 2048;
  float* p = sc + (size_t)blockIdx.x * S;
  int t = threadIdx.x;
  float4 v0 = ((const float4*)p)[2 * t];
  float4 v1 = ((const float4*)p)[2 * t + 1];
  float f[8] = {v0.x, v0.y, v0.z, v0.w, v1.x, v1.y, v1.z, v1.w};
  float m = f[0];
#pragma unroll
  for (int j = 1; j < 8; ++j) m = fmaxf(m, f[j]);
#pragma unroll
  for (int off = 32; off > 0; off >>= 1) m = fmaxf(m, __shfl_xor(m, off));
  __shared__ float r1[4], r2[4];
  int wv = t >> 6;
  if ((t & 63) == 0) r1[wv] = m;
  __syncthreads();
  m = fmaxf(fmaxf(r1[0], r1[1]), fmaxf(r1[2], r1[3]));
  float s = 0.f;
#pragma unroll
  for (int j = 0; j < 8; ++j) { f[j] = __expf(f[j] - m); s += f[j]; }
#pragma unroll
  for (int off = 32; off > 0; off >>= 1) s += __shfl_xor(s, off);
  if ((t & 63) == 0) r2[wv] = s;
  __syncthreads();
  s = r2[0] + r2[1] + r2[2] + r2[3];
  float inv = 1.f / s;
  unsigned u0 = f2bf(f[0] * inv), u1 = f2bf(f[1] * inv);
  unsigned u2 = f2bf(f[2] * inv), u3 = f2bf(f[3] * inv);
  unsigned u4 = f2bf(f[4] * inv), u5 = f2bf(f[5] * inv);
  unsigned u6 = f2bf(f[6] * inv), u7 = f2bf(f[7] * inv);
  uint4 o;
  o.x = u0 | (u1 << 16);
  o.y = u2 | (u3 << 16);
  o.z = u4 | (u5 << 16);
  o.w = u6 | (u7 << 16);
  ((uint4*)p)[t] = o;
}

// ---------------- read-ahead quadrant GEMM (BM=256, BN=128, BK=64) --------------
// 8 waves (2Mx4N), per-wave 128x32. Phases = C-quadrants; phase P issues the
// ds_reads consumed by phase P+1, then waits lgkmcnt(N_just_issued) -> drains
// only the PREVIOUS phase's reads; MFMA never waits on same-phase reads.
// bn0 frags ping-pong across tiles (read P2(t-1), used P0(t)+P3(t)).
// Staging (GLL) in P1/P2/P3 only, each formally barrier-separated from its
// slot's readers' lgkm-drain. Steady vmcnt: P0:6, P1:6, P2:-, P3:8 (FIFO
// ledger); tails peeled (MODE1: 6,3,-,2; MODE2: 0,-,-,-).
template <bool OUT_BF16, bool HAS_BIAS, bool HAS_RES, bool GELU, bool VTR>
__global__ __launch_bounds__(512, 2) void gemm8(
    const bf16* __restrict__ A, int lda, size_t sA,
    const bf16* __restrict__ BT, int ldb, size_t sB,
    void* Cv, size_t sC,
    const float* __restrict__ bias, const float* res, bf16* vtr,
    int N, int K, float alpha, int gx, int gy) {
  __shared__ __align__(16) char lds_storage[65536 + 32768];
  const unsigned ldsAu = (unsigned)(uintptr_t)(c3*)lds_storage;
  const unsigned ldsBu = ldsAu + 65536;

  const int tid = threadIdx.x;
  const int lane = tid & 63;
  const int wave = tid >> 6;
  const int wm = wave >> 2, wn = wave & 3;
  const int lr = lane & 15, lq = lane >> 4;

  int id = blockIdx.x;
  const int nwg = gridDim.x;
  if ((nwg & 7) == 0) id = (id & 7) * (nwg >> 3) + (id >> 3);  // XCD swizzle
  const int bx = id % gx;
  const int rem = id / gx;
  const int by = rem % gy;
  const int bz = rem / gy;
  const int m0 = by * 256, n0 = bx * 128;

  // staging: thread -> (row = tid>>3, 16B chunk = tid&7); source column
  // pre-swizzled so linear GLL dest + XOR'd ds_read are consistent
  const int srow = tid >> 3;
  const int schunk = ((tid & 7) ^ (srow & 7)) * 8;
  const bf16* gA = A + sA * bz + (size_t)(m0 + srow) * lda + schunk;
  const bf16* gB = BT + sB * bz + (size_t)(n0 + srow) * ldb + schunk;

  const int nk = K >> 6;

  auto stA = [&](int tt, int h) {
    const bf16* s = gA + (size_t)(h * 128) * lda + (size_t)tt * 64;
    char* d = lds_storage + (((tt & 1) * 2 + h) << 14) + tid * 16;
    GLL(s, d);
    GLL(s + (size_t)64 * lda, d + 8192);
  };
  auto stB = [&](int tt, int h) {
    const bf16* s = gB + (size_t)(h * 64) * ldb + (size_t)tt * 64;
    char* d = lds_storage + 65536 + ((tt & 1) * 2 + h) * 8192 + tid * 16;
    GLL(s, d);
  };

  // ds_read bases: row*128 + ((chunk ^ (row&7))<<4); k-half flips addr bit6 (^64)
  const unsigned aB0 = (wm * 64 + lr) * 128 + ((lq ^ (lr & 7)) << 4);
  const unsigned bB0 = (wn * 16 + lr) * 128 + ((lq ^ (lr & 7)) << 4);

  floatx4 acc[2][2][4] = {};       // [mq][nq][mi]
  short8 am0k0[4], am0k1[4];       // m0-half A frags (tile t; refreshed in P2)
  short8 bn0Ak0, bn0Ak1, bn0Bk0, bn0Bk1;  // n0-half B frags, ping-pong

  // prologue: stage tiles 0,1 in steady issue order; retire through B1(0)
  stA(0, 0); stB(0, 0); stB(0, 1); stA(0, 1);
  stA(1, 0); stB(1, 0); stB(1, 1); stA(1, 1);
  vmwait<8>();
  __builtin_amdgcn_s_barrier();
  {  // prologue reads (the "P2(t-1)" for tile 0); drained by P0(0)'s lgkmcnt(2)
    const unsigned aA = ldsAu + aB0, aX = aA ^ 64;
    am0k0[0] = dsr<0>(aA); am0k0[1] = dsr<2048>(aA); am0k0[2] = dsr<4096>(aA); am0k0[3] = dsr<6144>(aA);
    am0k1[0] = dsr<0>(aX); am0k1[1] = dsr<2048>(aX); am0k1[2] = dsr<4096>(aX); am0k1[3] = dsr<6144>(aX);
    const unsigned bA = ldsBu + bB0;
    bn0Ak0 = dsr<0>(bA); bn0Ak1 = dsr<0>(bA ^ 64);
  }

  auto body = [&](int t, auto modeC, short8& bu0, short8& bu1, short8& bw0, short8& bw1) {
    constexpr int MODE = decltype(modeC)::value;  // 0 steady, 1 = nk-2, 2 = nk-1
    const unsigned As1 = ldsAu + ((((unsigned)t & 1) * 2 + 1) << 14);
    const unsigned Bs1 = ldsBu + (((unsigned)t & 1) * 2 + 1) * 8192;

    // ===== P0: MFMA (m0,n0) [am0 x bu]; read-ahead bn1 <- Bs1(t)
    short8 bn1k0, bn1k1;
    {
      const unsigned bA = Bs1 + bB0;
      bn1k0 = dsr<0>(bA); bn1k1 = dsr<0>(bA ^ 64);
    }
    lgkwait<2>();  // drains P2(t-1)'s 10 reads (am0, bu)
    __builtin_amdgcn_s_setprio(1);
#pragma unroll
    for (int mi = 0; mi < 4; ++mi) MFMA_(acc[0][0][mi], am0k0[mi], bu0);
#pragma unroll
    for (int mi = 0; mi < 4; ++mi) MFMA_(acc[0][0][mi], am0k1[mi], bu1);
    __builtin_amdgcn_s_setprio(0);
    vmwait<MODE == 2 ? 0 : 6>();
    __builtin_amdgcn_s_barrier();

    // ===== P1: MFMA (m0,n1) [am0 x bn1]; read-ahead am1 <- As1(t);
    //           stage A0(t+2), B0(t+2)
    short8 am1k0[4], am1k1[4];
    {
      const unsigned aA = As1 + aB0, aX = aA ^ 64;
      am1k0[0] = dsr<0>(aA); am1k0[1] = dsr<2048>(aA); am1k0[2] = dsr<4096>(aA); am1k0[3] = dsr<6144>(aA);
      am1k1[0] = dsr<0>(aX); am1k1[1] = dsr<2048>(aX); am1k1[2] = dsr<4096>(aX); am1k1[3] = dsr<6144>(aX);
    }
    if constexpr (MODE == 0) { stA(t + 2, 0); stB(t + 2, 0); }
    lgkwait<8>();  // drains P0's 2 reads (bn1)
    __builtin_amdgcn_s_setprio(1);
#pragma unroll
    for (int mi = 0; mi < 4; ++mi) MFMA_(acc[0][1][mi], am0k0[mi], bn1k0);
#pragma unroll
    for (int mi = 0; mi < 4; ++mi) MFMA_(acc[0][1][mi], am0k1[mi], bn1k1);
    __builtin_amdgcn_s_setprio(0);
    if constexpr (MODE == 0) { vmwait<6>(); __builtin_amdgcn_s_barrier(); }
    else if constexpr (MODE == 1) { vmwait<3>(); __builtin_amdgcn_s_barrier(); }

    // ===== P2: MFMA (m1,n1) [am1 x bn1]; read-ahead am0,bw <- As0/Bs0(t+1);
    //           stage B1(t+2)
    if constexpr (MODE < 2) {
      const unsigned aA = ldsAu + ((((unsigned)(t + 1) & 1) * 2) << 14) + aB0, aX = aA ^ 64;
      am0k0[0] = dsr<0>(aA); am0k0[1] = dsr<2048>(aA); am0k0[2] = dsr<4096>(aA); am0k0[3] = dsr<6144>(aA);
      am0k1[0] = dsr<0>(aX); am0k1[1] = dsr<2048>(aX); am0k1[2] = dsr<4096>(aX); am0k1[3] = dsr<6144>(aX);
      const unsigned bA = ldsBu + (((unsigned)(t + 1) & 1) * 2) * 8192 + bB0;
      bw0 = dsr<0>(bA); bw1 = dsr<0>(bA ^ 64);
    }
    if constexpr (MODE == 0) stB(t + 2, 1);
    if constexpr (MODE < 2) lgkwait<10>();  // drains P1's 8 reads (am1)
    else lgkwait<0>();
    __builtin_amdgcn_s_setprio(1);
#pragma unroll
    for (int mi = 0; mi < 4; ++mi) MFMA_(acc[1][1][mi], am1k0[mi], bn1k0);
#pragma unroll
    for (int mi = 0; mi < 4; ++mi) MFMA_(acc[1][1][mi], am1k1[mi], bn1k1);
    __builtin_amdgcn_s_setprio(0);
    if constexpr (MODE < 2) __builtin_amdgcn_s_barrier();

    // ===== P3: MFMA (m1,n0) [am1 x bu]; no reads; stage A1(t+2)
    if constexpr (MODE == 0) stA(t + 2, 1);
    __builtin_amdgcn_s_setprio(1);
#pragma unroll
    for (int mi = 0; mi < 4; ++mi) MFMA_(acc[1][0][mi], am1k0[mi], bu0);
#pragma unroll
    for (int mi = 0; mi < 4; ++mi) MFMA_(acc[1][0][mi], am1k1[mi], bu1);
    __builtin_amdgcn_s_setprio(0);
    if constexpr (MODE == 0) { vmwait<8>(); __builtin_amdgcn_s_barrier(); }
    else if constexpr (MODE == 1) { vmwait<2>(); __builtin_amdgcn_s_barrier(); }
  };

  // steady loop, 2x unrolled for bn0 ping-pong (nk-2 is even for all our K)
  for (int t = 0; t + 2 < nk; t += 2) {
    body(t, ic<0>{}, bn0Ak0, bn0Ak1, bn0Bk0, bn0Bk1);
    body(t + 1, ic<0>{}, bn0Bk0, bn0Bk1, bn0Ak0, bn0Ak1);
  }
  body(nk - 2, ic<1>{}, bn0Ak0, bn0Ak1, bn0Bk0, bn0Bk1);
  body(nk - 1, ic<2>{}, bn0Bk0, bn0Bk1, bn0Ak0, bn0Ak1);  // write refs unused

  // epilogue: C/D frag map col=lane&15, row=(lane>>4)*4+r [m89-verified]
  float* Cf = (float*)Cv;
  bf16* Cb = (bf16*)Cv;
  const size_t cb = sC * bz;
#pragma unroll
  for (int mq = 0; mq < 2; ++mq)
#pragma unroll
    for (int nq = 0; nq < 2; ++nq)
#pragma unroll
      for (int mi = 0; mi < 4; ++mi) {
        const int row = m0 + mq * 128 + wm * 64 + mi * 16 + lq * 4;
        const int col = n0 + nq * 64 + wn * 16 + lr;
        const float bb = HAS_BIAS ? bias[col] : 0.f;
#pragma unroll
        for (int r = 0; r < 4; ++r) {
          float val = acc[mq][nq][mi][r] * alpha + bb;
          if (GELU) val = 0.5f * val * (1.f + erff(val * 0.70710678118654752f));
          if (HAS_RES) val += res[(size_t)(row + r) * N + col];
          const size_t idx = cb + (size_t)(row + r) * N + col;
          if (OUT_BF16) Cb[idx] = __float2bfloat16(val);
          else Cf[idx] = val;
          if (VTR) {
            if (col >= 2048) {  // V columns: also write V^T [b][col-2048][row%S]
              const int rr = row + r;
              vtr[(((size_t)(rr >> 11) << 10) + (col - 2048)) * 2048 + (rr & 2047)] =
                  __float2bfloat16(val);
            }
          }
        }
      }
}

extern "C" void kernel_launch(void* const* d_in, const int* in_sizes, int n_in,
                              void* d_out, int out_size, void* d_ws, size_t ws_size,
                              hipStream_t stream) {
  const int B = 4, S = 2048, D = 1024, DFF = 4096;
  const int M = B * S;
  const float* x   = (const float*)d_in[0];
  const float* wq  = (const float*)d_in[1];
  const float* bq  = (const float*)d_in[2];
  const float* wk  = (const float*)d_in[3];
  const float* bk  = (const float*)d_in[4];
  const float* wv  = (const float*)d_in[5];
  const float* bv  = (const float*)d_in[6];
  const float* wo  = (const float*)d_in[7];
  const float* bo  = (const float*)d_in[8];
  const float* w1  = (const float*)d_in[9];
  const float* b1  = (const float*)d_in[10];
  const float* w2  = (const float*)d_in[11];
  const float* b2  = (const float*)d_in[12];
  const float* g1  = (const float*)d_in[13];
  const float* be1 = (const float*)d_in[14];
  const float* g2  = (const float*)d_in[15];
  const float* be2 = (const float*)d_in[16];
  float* out = (float*)d_out;

  // workspace arena:
  //  0-6 wqkvT  6-8 woT  8-16 w1T  16-24 w2T  24 bqkv  25-41 h (bf16 MxD)
  //  41-89 qkv (bf16 Mx3072) / later hidden (bf16 MxDFF, 41-105)
  //  89-105 vT [4][D][S] bf16 (written by QKV epilogue)
  //  105+  scores fp32, chunk*16MB
  char* wsb = (char*)d_ws;
  const size_t MB1 = 1ull << 20;
  bf16* wqkvT = (bf16*)(wsb + 0 * MB1);
  bf16* woT   = (bf16*)(wsb + 6 * MB1);
  bf16* w1T   = (bf16*)(wsb + 8 * MB1);
  bf16* w2T   = (bf16*)(wsb + 16 * MB1);
  float* bqkv = (float*)(wsb + 24 * MB1);
  bf16* h     = (bf16*)(wsb + 25 * MB1);
  bf16* qkv   = (bf16*)(wsb + 41 * MB1);
  bf16* hidden = (bf16*)(wsb + 41 * MB1);
  bf16* vTall = (bf16*)(wsb + 89 * MB1);
  float* sc   = (float*)(wsb + 105 * MB1);

  int chunk = 1;
  if (ws_size > 105 * MB1) {
    size_t c = (ws_size - 105 * MB1) / (16 * MB1);
    chunk = (int)(c > 4 ? 4 : (c < 1 ? 1 : c));
  }

  dim3 tb(32, 8);
  wtrans_kernel<<<dim3(32, 32), tb, 0, stream>>>(wq, wqkvT, D, D);
  wtrans_kernel<<<dim3(32, 32), tb, 0, stream>>>(wk, wqkvT + (size_t)1024 * 1024, D, D);
  wtrans_kernel<<<dim3(32, 32), tb, 0, stream>>>(wv, wqkvT + (size_t)2048 * 1024, D, D);
  wtrans_kernel<<<dim3(32, 32), tb, 0, stream>>>(wo, woT, D, D);
  wtrans_kernel<<<dim3(128, 32), tb, 0, stream>>>(w1, w1T, D, DFF);
  wtrans_kernel<<<dim3(32, 128), tb, 0, stream>>>(w2, w2T, DFF, D);
  hipMemcpyAsync(bqkv, bq, 4096, hipMemcpyDeviceToDevice, stream);
  hipMemcpyAsync(bqkv + 1024, bk, 4096, hipMemcpyDeviceToDevice, stream);
  hipMemcpyAsync(bqkv + 2048, bv, 4096, hipMemcpyDeviceToDevice, stream);

  // h = LN1(x)
  ln_kernel<<<M, 256, 0, stream>>>(x, g1, be1, h);

  // qkv = h @ [wq|wk|wv] + biases; V columns also emitted transposed into vTall
  gemm8<true, true, false, false, true><<<24 * 32, 512, 0, stream>>>(
      h, D, 0, wqkvT, D, 0, qkv, 0, bqkv, nullptr, vTall, 3072, D, 1.f, 24, 32);

  for (int b0 = 0; b0 < B; b0 += chunk) {
    int c = (B - b0 < chunk) ? (B - b0) : chunk;
    // scores = q @ k^T * 0.125 (fp32)
    gemm8<false, false, false, false, false><<<128 * c, 512, 0, stream>>>(
        qkv + (size_t)b0 * S * 3072, 3072, (size_t)S * 3072,
        qkv + (size_t)b0 * S * 3072 + 1024, 3072, (size_t)S * 3072,
        sc, (size_t)S * S, nullptr, nullptr, nullptr, S, D, 0.125f, 16, 8);
    softmax_kernel<<<c * S, 256, 0, stream>>>(sc);
    // ctx = probs @ vT^T (probs bf16 in-place over fp32 rows, pitch 2S)
    gemm8<true, false, false, false, false><<<64 * c, 512, 0, stream>>>(
        (const bf16*)sc, 2 * S, (size_t)S * 2 * S,
        vTall + (size_t)b0 * D * S, S, (size_t)D * S,
        h + (size_t)b0 * S * D, (size_t)S * D, nullptr, nullptr, nullptr, D, S, 1.f, 8, 8);
  }

  // x2 = ctx @ wo + bo + x -> d_out (fp32)
  gemm8<false, true, true, false, false><<<8 * 32, 512, 0, stream>>>(
      h, D, 0, woT, D, 0, out, 0, bo, x, nullptr, D, D, 1.f, 8, 32);

  // h = LN2(x2)
  ln_kernel<<<M, 256, 0, stream>>>(out, g2, be2, h);

  // hidden = gelu(h @ w1 + b1)
  gemm8<true, true, false, true, false><<<32 * 32, 512, 0, stream>>>(
      h, D, 0, w1T, D, 0, hidden, 0, b1, nullptr, nullptr, DFF, D, 1.f, 32, 32);

  // out = hidden @ w2 + b2 + x2 (in-place residual)
  gemm8<false, true, true, false, false><<<8 * 32, 512, 0, stream>>>(
      hidden, DFF, 0, w2T, DFF, 0, out, 0, b2, out, nullptr, D, DFF, 1.f, 8, 32);
}